// Round 10
// baseline (844.557 us; speedup 1.0000x reference)
//
#include <hip/hip_runtime.h>

#define Bdim 64
#define Tdim 512
#define Idim 512
#define Hdim 512
#define CLIPV 10.0f
#define NREGG 50        // reg-resident groups of 4 dwords (200 dwords/thread)
#define NLDSG 14        // LDS-resident groups (112 KB)

typedef __attribute__((ext_vector_type(4))) float f32x4;
typedef __attribute__((ext_vector_type(8))) short bf16x8;
typedef _Float16 half2v __attribute__((ext_vector_type(2)));
typedef __fp16 fp16x2 __attribute__((ext_vector_type(2)));

__device__ __forceinline__ ushort f2bf(float f) {
    unsigned u = __builtin_bit_cast(unsigned, f);
    u += 0x7fffu + ((u >> 16) & 1u);   // round-to-nearest-even
    return (ushort)(u >> 16);
}
__device__ __forceinline__ float bf2f(ushort h) {
    return __builtin_bit_cast(float, (unsigned)h << 16);
}
__device__ __forceinline__ void split_bf(float f, ushort& h, ushort& l) {
    h = f2bf(f);
    l = f2bf(f - bf2f(h));
}
__device__ __forceinline__ float dot2acc(uint r, uint h2, float acc) {
#if __has_builtin(__builtin_amdgcn_fdot2)
    return __builtin_amdgcn_fdot2(__builtin_bit_cast(half2v, r),
                                  __builtin_bit_cast(half2v, h2), acc, false);
#else
    half2v a = __builtin_bit_cast(half2v, r);
    half2v b = __builtin_bit_cast(half2v, h2);
    return acc + (float)a.x * (float)b.x + (float)a.y * (float)b.y;
#endif
}
__device__ __forceinline__ uint packf16(float a, float b) {
    _Float16 fa = (_Float16)a, fb = (_Float16)b;
    return (uint)__builtin_bit_cast(ushort, fa) |
           ((uint)__builtin_bit_cast(ushort, fb) << 16);
}
__device__ __forceinline__ uint pkrtz(float a, float b) {
#if __has_builtin(__builtin_amdgcn_cvt_pkrtz)
    fp16x2 p = __builtin_amdgcn_cvt_pkrtz(a, b);
    return __builtin_bit_cast(uint, p);
#else
    return packf16(a, b);
#endif
}
__device__ __forceinline__ float fastrcp(float x) {
#if __has_builtin(__builtin_amdgcn_rcpf)
    return __builtin_amdgcn_rcpf(x);
#else
    return 1.0f / x;
#endif
}

// ---- cast + transpose W into hi/lo bf16 (feed-forward GEMM operands) ----
__global__ __launch_bounds__(256) void transpose_w_kernel(const float* __restrict__ w,
                                                          ushort* __restrict__ wth,
                                                          ushort* __restrict__ wtl) {
    int idx = blockIdx.x * 256 + threadIdx.x;
    int k = idx >> 9, n = idx & 511;
    ushort h, l;
    split_bf(w[idx], h, l);
    wth[n * Idim + k] = h;
    wtl[n * Idim + k] = l;
}

// ---- pack R (fp16 pairs): group g = 2j+half, consuming thread t=(w,l) ----
// kp = w*32 + j ; col = half*256 + l*4 + r ; rpk[g*2048 + t*4 + r]
__global__ __launch_bounds__(256) void pack_r_kernel(const float* __restrict__ Rw,
                                                     uint* __restrict__ rpk) {
    int d = blockIdx.x * 256 + threadIdx.x;      // 0..131071
    int g = d >> 11;
    int rem = d & 2047;
    int t = rem >> 2, r = rem & 3;
    int j = g >> 1, half = g & 1;
    int w = t >> 6, l = t & 63;
    int kp = w * 32 + j;
    int c  = half * 256 + l * 4 + r;
    rpk[d] = packf16(Rw[(size_t)(2 * kp) * Hdim + c],
                     Rw[(size_t)(2 * kp + 1) * Hdim + c]);
}

// ---- phase 1: pre = x @ W + bias via bf16x3 MFMA ----
#define BM 128
#define BN 128
#define BK 32
__global__ __launch_bounds__(256) void gemm_xw(
    const float* __restrict__ A,
    const ushort* __restrict__ Bth,
    const ushort* __restrict__ Btl,
    const float* __restrict__ bias,
    float* __restrict__ C,
    int M, int N, int K)
{
    __shared__ ushort AsH[BM][BK];
    __shared__ ushort AsL[BM][BK];
    __shared__ ushort BsH[BN][BK];
    __shared__ ushort BsL[BN][BK];
    int bm = blockIdx.x, bn = blockIdx.y;
    int tid = threadIdx.x;
    int wave = tid >> 6, lane = tid & 63;
    int wr = wave >> 1, wc = wave & 1;
    f32x4 acc[4][4] = {};
    const int row0 = bm * BM, col0 = bn * BN;
    const int sr = tid >> 1;
    const int sc = (tid & 1) * 16;

    for (int kt = 0; kt < K; kt += BK) {
        const float* gA = A + (size_t)(row0 + sr) * K + kt + sc;
        #pragma unroll
        for (int q = 0; q < 4; ++q) {
            float4 v = *(const float4*)(gA + q * 4);
            ushort4 h4, l4;
            split_bf(v.x, h4.x, l4.x);
            split_bf(v.y, h4.y, l4.y);
            split_bf(v.z, h4.z, l4.z);
            split_bf(v.w, h4.w, l4.w);
            *(ushort4*)&AsH[sr][sc + q * 4] = h4;
            *(ushort4*)&AsL[sr][sc + q * 4] = l4;
        }
        const int4* gBh = (const int4*)(Bth + (size_t)(col0 + sr) * K + kt + sc);
        *(int4*)&BsH[sr][sc]     = gBh[0];
        *(int4*)&BsH[sr][sc + 8] = gBh[1];
        const int4* gBl = (const int4*)(Btl + (size_t)(col0 + sr) * K + kt + sc);
        *(int4*)&BsL[sr][sc]     = gBl[0];
        *(int4*)&BsL[sr][sc + 8] = gBl[1];
        __syncthreads();

        const int r = lane & 15, kg = lane >> 4;
        bf16x8 ah[4], al[4], bh[4], bl[4];
        #pragma unroll
        for (int m = 0; m < 4; ++m) {
            ah[m] = *(const bf16x8*)&AsH[wr * 64 + m * 16 + r][kg * 8];
            al[m] = *(const bf16x8*)&AsL[wr * 64 + m * 16 + r][kg * 8];
        }
        #pragma unroll
        for (int n = 0; n < 4; ++n) {
            bh[n] = *(const bf16x8*)&BsH[wc * 64 + n * 16 + r][kg * 8];
            bl[n] = *(const bf16x8*)&BsL[wc * 64 + n * 16 + r][kg * 8];
        }
        #pragma unroll
        for (int m = 0; m < 4; ++m)
            #pragma unroll
            for (int n = 0; n < 4; ++n) {
                acc[m][n] = __builtin_amdgcn_mfma_f32_16x16x32_bf16(ah[m], bh[n], acc[m][n], 0, 0, 0);
                acc[m][n] = __builtin_amdgcn_mfma_f32_16x16x32_bf16(ah[m], bl[n], acc[m][n], 0, 0, 0);
                acc[m][n] = __builtin_amdgcn_mfma_f32_16x16x32_bf16(al[m], bh[n], acc[m][n], 0, 0, 0);
            }
        __syncthreads();
    }

    const int cl = lane & 15, rg = lane >> 4;
    #pragma unroll
    for (int n = 0; n < 4; ++n) {
        int gc = col0 + wc * 64 + n * 16 + cl;
        float bv = bias[gc];
        #pragma unroll
        for (int m = 0; m < 4; ++m) {
            int gr = row0 + wr * 64 + m * 16 + rg * 4;
            #pragma unroll
            for (int r2 = 0; r2 < 4; ++r2)
                C[(size_t)(gr + r2) * N + gc] = acc[m][n][r2] + bv;
        }
    }
}

// ---- phase 2: recurrence. 64 WGs (1 row each), 512 threads, zero cross-WG sync.
// Wave w owns k-eighth w AND output cols [w*64, w*64+64). h stays IN REGISTERS:
// finalize lane i<32 computes cols w*64+2i,+2i+1 and packs them into hval —
// exactly the pair readlane(hval, j) consumes next step. One barrier per step.
__global__ __launch_bounds__(512, 2) void rnn_reg_kernel(
    const uint* __restrict__ Rpk,    // [131072] packed fp16 pairs
    float* __restrict__ out,         // [B][T][H]: pre -> h in place
    float* __restrict__ hlast,       // [B][H]
    const float* __restrict__ h0)    // [B][H]
{
    __shared__ uint Rlds[NLDSG * 2048];     // 112 KB
    __shared__ float part[2][8][Hdim];      // 32 KB, parity double-buffered

    const int tid = threadIdx.x;
    const int row = blockIdx.x;
    const int w   = tid >> 6;               // wave = k-eighth = col block
    const int l   = tid & 63;
    const int li  = l & 31;
    const int fcol = w * 64 + 2 * li;       // finalize columns fcol, fcol+1

    // register-resident R: 50 x uint4 = 200 dwords
    uint4 rr4[NREGG];
    const uint* rbase = Rpk + tid * 4;
    #pragma unroll
    for (int i = 0; i < NREGG; ++i)
        rr4[i] = *(const uint4*)(rbase + i * 2048);
    // LDS-resident R: 14 groups, dense stride-16B layout (2-way banks, free)
    #pragma unroll
    for (int g = 0; g < NLDSG; ++g)
        *(uint4*)&Rlds[g * 2048 + tid * 4] =
            *(const uint4*)(rbase + (NREGG + g) * 2048);

    // h in-register: lane i (i<32 authoritative) holds pair w*32+i
    uint hval = packf16(h0[row * Hdim + fcol], h0[row * Hdim + fcol + 1]);
    __syncthreads();

    float* orow = out + (size_t)row * Tdim * Hdim;
    float2 pre = *(const float2*)(orow + fcol);       // pre for t=0

    for (int t = 0; t < Tdim; ++t, orow += Hdim) {
        // prefetch pre for t+1: orow[t+1] still holds untouched GEMM output
        float2 pre_nxt = *(const float2*)(orow + Hdim + fcol);

        float a0 = 0.f, a1 = 0.f, a2 = 0.f, a3 = 0.f;
        float a4 = 0.f, a5 = 0.f, a6 = 0.f, a7 = 0.f;
        // register chunks j = 0..24: cols l*4+r (a0-3) and 256+l*4+r (a4-7)
        #pragma unroll
        for (int j = 0; j < NREGG / 2; ++j) {
            uint hvi = __builtin_amdgcn_readlane(hval, j);
            uint4 rA = rr4[2 * j], rB = rr4[2 * j + 1];
            a0 = dot2acc(rA.x, hvi, a0);
            a1 = dot2acc(rA.y, hvi, a1);
            a2 = dot2acc(rA.z, hvi, a2);
            a3 = dot2acc(rA.w, hvi, a3);
            a4 = dot2acc(rB.x, hvi, a4);
            a5 = dot2acc(rB.y, hvi, a5);
            a6 = dot2acc(rB.z, hvi, a6);
            a7 = dot2acc(rB.w, hvi, a7);
        }
        // LDS chunks j = 25..31
        #pragma unroll
        for (int j = 0; j < NLDSG / 2; ++j) {
            uint hvi = __builtin_amdgcn_readlane(hval, NREGG / 2 + j);
            uint4 rA = *(const uint4*)&Rlds[(2 * j) * 2048 + tid * 4];
            uint4 rB = *(const uint4*)&Rlds[(2 * j + 1) * 2048 + tid * 4];
            a0 = dot2acc(rA.x, hvi, a0);
            a1 = dot2acc(rA.y, hvi, a1);
            a2 = dot2acc(rA.z, hvi, a2);
            a3 = dot2acc(rA.w, hvi, a3);
            a4 = dot2acc(rB.x, hvi, a4);
            a5 = dot2acc(rB.y, hvi, a5);
            a6 = dot2acc(rB.z, hvi, a6);
            a7 = dot2acc(rB.w, hvi, a7);
        }
        const int p = t & 1;
        *(f32x4*)&part[p][w][l * 4]       = (f32x4){a0, a1, a2, a3};
        *(f32x4*)&part[p][w][256 + l * 4] = (f32x4){a4, a5, a6, a7};
        __syncthreads();                                  // the ONLY barrier

        // finalize: all lanes compute cols fcol,fcol+1 (lanes>=32 redundant)
        float s0 = pre.x, s1 = pre.y;
        #pragma unroll
        for (int e = 0; e < 8; ++e) {
            float2 pp = *(const float2*)&part[p][e][fcol];
            s0 += pp.x; s1 += pp.y;
        }
        s0 = fminf(fmaxf(s0, -CLIPV), CLIPV);
        s1 = fminf(fmaxf(s1, -CLIPV), CLIPV);
        float e0 = __expf(2.0f * s0), e1 = __expf(2.0f * s1);
        float v0 = (e0 - 1.0f) * fastrcp(e0 + 1.0f);      // tanh
        float v1 = (e1 - 1.0f) * fastrcp(e1 + 1.0f);
        hval = pkrtz(v0, v1);                             // h stays in-register
        if (l < 32) {
            *(float2*)(orow + fcol) = make_float2(v0, v1);
            if (t == Tdim - 1)
                *(float2*)&hlast[row * Hdim + fcol] = make_float2(v0, v1);
        }
        pre = pre_nxt;
        // no second barrier: hval same-wave; part WAR parity-protected
    }
}

extern "C" void kernel_launch(void* const* d_in, const int* in_sizes, int n_in,
                              void* d_out, int out_size, void* d_ws, size_t ws_size,
                              hipStream_t stream) {
    const float* x    = (const float*)d_in[0];
    const float* W    = (const float*)d_in[1];
    const float* R    = (const float*)d_in[2];
    const float* bias = (const float*)d_in[3];
    const float* h0   = (const float*)d_in[4];
    float* out = (float*)d_out;

    ushort* wth = (ushort*)d_ws;                                // 512 KB
    ushort* wtl = wth + (size_t)Idim * Hdim;                    // 512 KB
    uint* rpk   = (uint*)((char*)d_ws + (1u << 20));            // 512 KB

    transpose_w_kernel<<<(Idim * Hdim + 255) / 256, 256, 0, stream>>>(W, wth, wtl);
    pack_r_kernel<<<512, 256, 0, stream>>>(R, rpk);

    dim3 gg(Bdim * Tdim / BM, Hdim / BN);
    gemm_xw<<<gg, 256, 0, stream>>>(x, wth, wtl, bias, out, Bdim * Tdim, Hdim, Idim);

    rnn_reg_kernel<<<Bdim, 512, 0, stream>>>(
        rpk, out, out + (size_t)Bdim * Tdim * Hdim, h0);
}